// Round 7
// baseline (611.932 us; speedup 1.0000x reference)
//
#include <hip/hip_runtime.h>

typedef unsigned int u32;
typedef unsigned short u16;
typedef __attribute__((ext_vector_type(8))) short short8;
typedef __attribute__((ext_vector_type(4))) float floatx4;

union F8 { uint4 u4; short8 s8; };

__device__ __forceinline__ float bf2f(u32 lo16) { return __uint_as_float(lo16 << 16); }
__device__ __forceinline__ u16 f2bf(float f) {
    u32 u = __float_as_uint(f);
    return (u16)((u + 0x7FFFu + ((u >> 16) & 1u)) >> 16);
}
__device__ __forceinline__ u32 pack2(float a, float b) {
    return (u32)f2bf(a) | ((u32)f2bf(b) << 16);
}

// ---------------- k_front: blocks [0,64)=Wc, 64=c1, [65,65+NS)=stage, rest=count
__global__ __launch_bounds__(256) void k_front(
    const float* __restrict__ x, const float* __restrict__ perb,
    const int* __restrict__ erow,
    const float* __restrict__ Won, const float* __restrict__ W1,
    const float* __restrict__ b_on, const float* __restrict__ b1,
    u16* __restrict__ XS, int* __restrict__ cnt,
    float* __restrict__ Wc, float* __restrict__ c1,
    int N, int E, int NS)
{
    int b = blockIdx.x, t = threadIdx.x;
    if (b < 64) {
        int tid = b * 256 + t;
        int i = tid >> 7, j = tid & 127;
        float s = 0.f;
        for (int k = 0; k < 128; k++) s = fmaf(Won[i * 128 + k], W1[k * 128 + j], s);
        Wc[tid] = s;
    } else if (b == 64) {
        if (t < 128) {
            float s = b1[t];
            for (int k = 0; k < 128; k++) s = fmaf(b_on[k], W1[k * 128 + t], s);
            c1[t] = s;
        }
    } else if (b < 65 + NS) {
        int tid = (b - 65) * 256 + t;
        if (tid < N * 32) {
            int row = tid >> 5, seg = tid & 31;
            float4 xv = *(const float4*)(x + (size_t)row * 128 + seg * 4);
            float4 pv = *(const float4*)(perb + (size_t)row * 128 + seg * 4);
            u16* r = XS + (size_t)row * 256 + seg * 4;
            *(uint2*)r = make_uint2(pack2(xv.x, xv.y), pack2(xv.z, xv.w));
            *(uint2*)(r + 128) = make_uint2(pack2(xv.x + pv.x, xv.y + pv.y), pack2(xv.z + pv.z, xv.w + pv.w));
        }
    } else {
        int e = (b - 65 - NS) * 256 + t;
        if (e < E) atomicAdd(&cnt[erow[e]], 1);
    }
}

#define SCAN_CHUNK 512
// ---------------- k_mid: blocks [0,4)=wfrag, rest=bsum
__global__ __launch_bounds__(256) void k_mid(
    const float* __restrict__ Won, const float* __restrict__ Wtg,
    const float* __restrict__ Wc, const float* __restrict__ W2,
    u16* __restrict__ Wfrag,
    const int* __restrict__ cnt, int* __restrict__ bsum, int N, int nbscan)
{
    __shared__ int red[256];
    int b = blockIdx.x, t = threadIdx.x;
    if (b < 4) {
        int mat = b;
        const float* W = mat == 0 ? Won : (mat == 1 ? Wtg : (mat == 2 ? Wc : W2));
        uint4* out = (uint4*)(Wfrag + (size_t)mat * 16384);
        for (int s = t; s < 2048; s += 256) {
            int lane = s & 63;
            int n = ((s >> 8) << 4) + (lane & 15);
            int k0 = ((s >> 6) & 3) * 32 + (lane >> 4) * 8;
            u32 p[4];
#pragma unroll
            for (int jj = 0; jj < 4; jj++) {
                float a = W[(size_t)(k0 + 2 * jj) * 128 + n];
                float bb = W[(size_t)(k0 + 2 * jj + 1) * 128 + n];
                p[jj] = pack2(a, bb);
            }
            out[s] = make_uint4(p[0], p[1], p[2], p[3]);
        }
    } else {
        int bb = b - 4;
        if (bb >= nbscan) return;
        int i0 = bb * SCAN_CHUNK + t;
        int s = 0;
        if (i0 < N) s += cnt[i0];
        if (i0 + 256 < N) s += cnt[i0 + 256];
        red[t] = s; __syncthreads();
        for (int d = 128; d > 0; d >>= 1) { if (t < d) red[t] += red[t + d]; __syncthreads(); }
        if (t == 0) bsum[bb] = red[0];
    }
}

__global__ __launch_bounds__(256) void k_scan2(
    const int* __restrict__ cnt, const int* __restrict__ bsum,
    int* __restrict__ off, int N, int E)
{
    int b = blockIdx.x, t = threadIdx.x;
    __shared__ int red[256];
    __shared__ int sc[257];
    __shared__ int sbase;
    int ps = 0;
    for (int i = t; i < b; i += 256) ps += bsum[i];
    red[t] = ps; __syncthreads();
    for (int d = 128; d > 0; d >>= 1) { if (t < d) red[t] += red[t + d]; __syncthreads(); }
    if (t == 0) sbase = red[0];
    __syncthreads();
    int base = b * SCAN_CHUNK;
    int i0 = base + 2 * t, i1 = i0 + 1;
    int v0 = (i0 < N) ? cnt[i0] : 0;
    int v1 = (i1 < N) ? cnt[i1] : 0;
    int tsum = v0 + v1;
    sc[t] = tsum; __syncthreads();
    for (int d = 1; d < 256; d <<= 1) {
        int add = (t >= d) ? sc[t - d] : 0;
        __syncthreads();
        sc[t] += add;
        __syncthreads();
    }
    int excl = sbase + sc[t] - tsum;
    if (i0 < N) off[i0] = excl;
    if (i1 < N) off[i1] = excl + v0;
    if (b == 0 && t == 0) off[N] = E;
}

// ---------------- k_scatter: packed (col,w) single 8B store; cnt countdown
__global__ void k_scatter(const int* __restrict__ row, const int* __restrict__ col, const float* __restrict__ w,
                          const int* __restrict__ off, int* __restrict__ cnt,
                          uint2* __restrict__ cpack, int E) {
    int e = blockIdx.x * blockDim.x + threadIdx.x;
    if (e < E) {
        int r = row[e];
        int pos = off[r] + atomicSub(&cnt[r], 1) - 1;
        cpack[pos] = make_uint2((u32)col[e], __float_as_uint(w[e]));
    }
}

// ---------------- k_agg: wave per node; col-range blocked so gathers are L2-resident
__global__ __launch_bounds__(256) void k_agg(
    const u16* __restrict__ XS, const int* __restrict__ off,
    const uint2* __restrict__ cpack, u16* __restrict__ AG, int N)
{
    int wave = threadIdx.x >> 6, lane = threadIdx.x & 63;
    int node = blockIdx.x * 4 + wave;
    if (node >= N) return;
    int o0 = off[node], o1 = off[node + 1];
    float a0 = 0.f, a1 = 0.f, a2 = 0.f, a3 = 0.f;
    const int slice = (N + 7) >> 3;   // 8 passes, each slice ~3.2MB of XS -> fits per-XCD L2
#pragma unroll 1
    for (int p = 0; p < 8; p++) {
        int lo = p * slice;
        int hi = lo + slice;
#pragma unroll 2
        for (int e = o0; e < o1; e++) {
            uint2 rec = cpack[e];
            int c = (int)rec.x;
            if (c < lo || c >= hi) continue;   // wave-uniform scalar branch
            float w = __uint_as_float(rec.y);
            uint2 v = ((const uint2*)(XS + (size_t)c * 256))[lane];
            a0 = fmaf(w, bf2f(v.x & 0xffffu), a0);
            a1 = fmaf(w, bf2f(v.x >> 16), a1);
            a2 = fmaf(w, bf2f(v.y & 0xffffu), a2);
            a3 = fmaf(w, bf2f(v.y >> 16), a3);
        }
    }
    ((uint2*)(AG + (size_t)node * 256))[lane] = make_uint2(pack2(a0, a1), pack2(a2, a3));
}

// ---------------- k_hemb: W fragments staged in LDS (Won + Wc = 64 KB)
__global__ __launch_bounds__(256) void k_hemb(
    const u16* __restrict__ AG, const u16* __restrict__ Wfrag,
    const float* __restrict__ c1, const float* __restrict__ b_on,
    const float* __restrict__ x, const float* __restrict__ perb,
    u16* __restrict__ h1x, u16* __restrict__ h1y, float* __restrict__ out, int N)
{
    __shared__ uint4 sW[4096];
    const int wave = threadIdx.x >> 6, lane = threadIdx.x & 63;
    const int m = lane & 15, q = lane >> 4;
    const int grow = blockIdx.x * 64 + wave * 16 + m;
    const int rc = grow < N ? grow : N - 1;
    const bool valid = grow < N;
    const u16* ar = AG + (size_t)rc * 256;
    const uint4* wfWon = (const uint4*)Wfrag;
    const uint4* wfWc  = (const uint4*)(Wfrag + 2 * 16384);
    short8 fa[4], fb[4];
#pragma unroll
    for (int ks = 0; ks < 4; ks++) {
        int c0 = ks * 32 + q * 8;
        F8 t;
        t.u4 = *(const uint4*)(ar + c0);       fa[ks] = t.s8;
        t.u4 = *(const uint4*)(ar + 128 + c0); fb[ks] = t.s8;
    }
#pragma unroll
    for (int i = threadIdx.x; i < 2048; i += 256) {
        sW[i]        = wfWon[i];
        sW[i + 2048] = wfWc[i];
    }
    __syncthreads();
#pragma unroll 2
    for (int ct = 0; ct < 8; ct++) {
        floatx4 ax = {0.f, 0.f, 0.f, 0.f}, ay = {0.f, 0.f, 0.f, 0.f}, em = {0.f, 0.f, 0.f, 0.f};
#pragma unroll
        for (int ks = 0; ks < 4; ks++) {
            F8 wc, wo;
            wo.u4 = sW[(ct * 4 + ks) * 64 + lane];
            wc.u4 = sW[2048 + (ct * 4 + ks) * 64 + lane];
            ax = __builtin_amdgcn_mfma_f32_16x16x32_bf16(wc.s8, fa[ks], ax, 0, 0, 0);
            ay = __builtin_amdgcn_mfma_f32_16x16x32_bf16(wc.s8, fb[ks], ay, 0, 0, 0);
            em = __builtin_amdgcn_mfma_f32_16x16x32_bf16(wo.s8, fb[ks], em, 0, 0, 0);
        }
        if (valid) {
            int c0 = ct * 16 + q * 4;
            float4 cv = *(const float4*)(c1 + c0);
            float4 bo = *(const float4*)(b_on + c0);
            float4 xv = *(const float4*)(x + (size_t)grow * 128 + c0);
            float4 pv = *(const float4*)(perb + (size_t)grow * 128 + c0);
            *(uint2*)(h1x + (size_t)grow * 128 + c0) =
                make_uint2(pack2(ax[0] + cv.x, ax[1] + cv.y), pack2(ax[2] + cv.z, ax[3] + cv.w));
            *(uint2*)(h1y + (size_t)grow * 128 + c0) =
                make_uint2(pack2(ay[0] + cv.x, ay[1] + cv.y), pack2(ay[2] + cv.z, ay[3] + cv.w));
            float4 o;
            o.x = xv.x + pv.x + em[0] + bo.x;
            o.y = xv.y + pv.y + em[1] + bo.y;
            o.z = xv.z + pv.z + em[2] + bo.z;
            o.w = xv.w + pv.w + em[3] + bo.w;
            *(float4*)(out + (size_t)grow * 128 + c0) = o;
        }
    }
}

// ---------------- k_bnstats (+ fused bnfin via ticket)
__global__ __launch_bounds__(256) void k_bnstats(
    const u32* __restrict__ h1x32, const u32* __restrict__ h1y32,
    float* __restrict__ sums, int* __restrict__ tick,
    const float* __restrict__ g, const float* __restrict__ beta,
    float* __restrict__ bnp, int N)
{
    int c2 = threadIdx.x & 63, gg = threadIdx.x >> 6;
    int per = (N + gridDim.x - 1) / gridDim.x;
    int r0 = blockIdx.x * per, r1 = r0 + per;
    if (r1 > N) r1 = N;
    float s[8] = {0.f, 0.f, 0.f, 0.f, 0.f, 0.f, 0.f, 0.f};
    for (int r = r0 + gg; r < r1; r += 4) {
        u32 vx = h1x32[(size_t)r * 64 + c2];
        float lo = bf2f(vx & 0xffffu), hi = bf2f(vx >> 16);
        s[0] += lo; s[1] = fmaf(lo, lo, s[1]); s[2] += hi; s[3] = fmaf(hi, hi, s[3]);
        u32 vy = h1y32[(size_t)r * 64 + c2];
        lo = bf2f(vy & 0xffffu); hi = bf2f(vy >> 16);
        s[4] += lo; s[5] = fmaf(lo, lo, s[5]); s[6] += hi; s[7] = fmaf(hi, hi, s[7]);
    }
    __shared__ float red[256][8];
    __shared__ int lastflag;
#pragma unroll
    for (int k = 0; k < 8; k++) red[threadIdx.x][k] = s[k];
    __syncthreads();
    if (gg == 0) {
        float v[8];
#pragma unroll
        for (int k = 0; k < 8; k++)
            v[k] = red[c2][k] + red[c2 + 64][k] + red[c2 + 128][k] + red[c2 + 192][k];
        int c0 = 2 * c2, c1i = c0 + 1;
        atomicAdd(&sums[c0], v[0]);        atomicAdd(&sums[128 + c0], v[1]);
        atomicAdd(&sums[c1i], v[2]);       atomicAdd(&sums[128 + c1i], v[3]);
        atomicAdd(&sums[256 + c0], v[4]);  atomicAdd(&sums[384 + c0], v[5]);
        atomicAdd(&sums[256 + c1i], v[6]); atomicAdd(&sums[384 + c1i], v[7]);
    }
    __syncthreads();
    if (threadIdx.x == 0) {
        __threadfence();
        int old = atomicAdd(tick, 1);
        lastflag = (old == (int)gridDim.x - 1) ? 1 : 0;
    }
    __syncthreads();
    if (lastflag && threadIdx.x < 128) {
        int d = threadIdx.x;
        float inv = 1.0f / (float)N;
        float s0 = atomicAdd(&sums[d], 0.f);
        float s1 = atomicAdd(&sums[128 + d], 0.f);
        float s2 = atomicAdd(&sums[256 + d], 0.f);
        float s3 = atomicAdd(&sums[384 + d], 0.f);
        float mux = s0 * inv;
        float varx = s1 * inv - mux * mux;
        float isx = rsqrtf(varx + 1e-5f);
        bnp[d]       = g[d] * isx;
        bnp[128 + d] = beta[d] - mux * g[d] * isx;
        float muy = s2 * inv;
        float vary = s3 * inv - muy * muy;
        float isy = rsqrtf(vary + 1e-5f);
        bnp[256 + d] = g[d] * isy;
        bnp[384 + d] = beta[d] - muy * g[d] * isy;
    }
}

// ---------------- k_loss (+ fused finalize via ticket; 64-slot spread loss accumulator)
__device__ __forceinline__ short8 bn_frag(const u16* hrow, const float* sc, const float* sh,
                                          int c0, float slope) {
    uint4 h = *(const uint4*)(hrow + c0);
    float4 s0 = *(const float4*)(sc + c0), s1 = *(const float4*)(sc + c0 + 4);
    float4 t0 = *(const float4*)(sh + c0), t1 = *(const float4*)(sh + c0 + 4);
    float v[8];
    v[0] = fmaf(bf2f(h.x & 0xffffu), s0.x, t0.x);
    v[1] = fmaf(bf2f(h.x >> 16),     s0.y, t0.y);
    v[2] = fmaf(bf2f(h.y & 0xffffu), s0.z, t0.z);
    v[3] = fmaf(bf2f(h.y >> 16),     s0.w, t0.w);
    v[4] = fmaf(bf2f(h.z & 0xffffu), s1.x, t1.x);
    v[5] = fmaf(bf2f(h.z >> 16),     s1.y, t1.y);
    v[6] = fmaf(bf2f(h.w & 0xffffu), s1.z, t1.z);
    v[7] = fmaf(bf2f(h.w >> 16),     s1.w, t1.w);
#pragma unroll
    for (int j = 0; j < 8; j++) v[j] = v[j] > 0.f ? v[j] : slope * v[j];
    F8 r;
    r.u4 = make_uint4(pack2(v[0], v[1]), pack2(v[2], v[3]), pack2(v[4], v[5]), pack2(v[6], v[7]));
    return r.s8;
}

__global__ __launch_bounds__(256) void k_loss(
    const u16* __restrict__ h1x, const u16* __restrict__ h1y,
    const u16* __restrict__ AG, const u16* __restrict__ Wfrag,
    const float* __restrict__ bnp, const float* __restrict__ prelu_a,
    const float* __restrict__ b2, const float* __restrict__ b_tg,
    float* __restrict__ lossb, int* __restrict__ tick, float* __restrict__ out, int N)
{
    __shared__ uint4 sW[4096];
    __shared__ float lred[4];
    __shared__ int lastflag;
    const int wave = threadIdx.x >> 6, lane = threadIdx.x & 63;
    const int m = lane & 15, q = lane >> 4;
    const int grow = blockIdx.x * 64 + wave * 16 + m;
    const int rc = grow < N ? grow : N - 1;
    const bool valid = grow < N;
    const float slope = prelu_a[0];
    const u16* hx = h1x + (size_t)rc * 128;
    const u16* hy = h1y + (size_t)rc * 128;
    const u16* ar = AG + (size_t)rc * 256;
    const uint4* wfTg = (const uint4*)(Wfrag + 1 * 16384);
    const uint4* wfW2 = (const uint4*)(Wfrag + 3 * 16384);
    short8 px8[4], py8[4], gx[4], gx2[4];
#pragma unroll
    for (int ks = 0; ks < 4; ks++) {
        int c0 = ks * 32 + q * 8;
        px8[ks] = bn_frag(hx, bnp, bnp + 128, c0, slope);
        py8[ks] = bn_frag(hy, bnp + 256, bnp + 384, c0, slope);
        F8 t;
        t.u4 = *(const uint4*)(ar + c0);       gx[ks] = t.s8;
        t.u4 = *(const uint4*)(ar + 128 + c0); gx2[ks] = t.s8;
    }
#pragma unroll
    for (int i = threadIdx.x; i < 2048; i += 256) {
        sW[i]        = wfTg[i];
        sW[i + 2048] = wfW2[i];
    }
    __syncthreads();
    float pp = 0.f, pt = 0.f, tt = 0.f, qq = 0.f, qs = 0.f, ss = 0.f;
#pragma unroll 2
    for (int ct = 0; ct < 8; ct++) {
        floatx4 ax = {0.f, 0.f, 0.f, 0.f}, ay = {0.f, 0.f, 0.f, 0.f};
        floatx4 atx = {0.f, 0.f, 0.f, 0.f}, aty = {0.f, 0.f, 0.f, 0.f};
#pragma unroll
        for (int ks = 0; ks < 4; ks++) {
            F8 w2, wt;
            wt.u4 = sW[(ct * 4 + ks) * 64 + lane];
            w2.u4 = sW[2048 + (ct * 4 + ks) * 64 + lane];
            ax  = __builtin_amdgcn_mfma_f32_16x16x32_bf16(w2.s8, px8[ks], ax, 0, 0, 0);
            ay  = __builtin_amdgcn_mfma_f32_16x16x32_bf16(w2.s8, py8[ks], ay, 0, 0, 0);
            atx = __builtin_amdgcn_mfma_f32_16x16x32_bf16(wt.s8, gx2[ks], atx, 0, 0, 0);
            aty = __builtin_amdgcn_mfma_f32_16x16x32_bf16(wt.s8, gx[ks], aty, 0, 0, 0);
        }
        int c0 = ct * 16 + q * 4;
        float4 bv = *(const float4*)(b2 + c0);
        float4 tb = *(const float4*)(b_tg + c0);
#pragma unroll
        for (int j = 0; j < 4; j++) {
            float bvj = j == 0 ? bv.x : (j == 1 ? bv.y : (j == 2 ? bv.z : bv.w));
            float tbj = j == 0 ? tb.x : (j == 1 ? tb.y : (j == 2 ? tb.z : tb.w));
            float pxv = ax[j] + bvj, txv = atx[j] + tbj;
            float pyv = ay[j] + bvj, tyv = aty[j] + tbj;
            pp = fmaf(pxv, pxv, pp); pt = fmaf(pxv, txv, pt); tt = fmaf(txv, txv, tt);
            qq = fmaf(pyv, pyv, qq); qs = fmaf(pyv, tyv, qs); ss = fmaf(tyv, tyv, ss);
        }
    }
    pp += __shfl_xor(pp, 16); pt += __shfl_xor(pt, 16); tt += __shfl_xor(tt, 16);
    qq += __shfl_xor(qq, 16); qs += __shfl_xor(qs, 16); ss += __shfl_xor(ss, 16);
    pp += __shfl_xor(pp, 32); pt += __shfl_xor(pt, 32); tt += __shfl_xor(tt, 32);
    qq += __shfl_xor(qq, 32); qs += __shfl_xor(qs, 32); ss += __shfl_xor(ss, 32);
    float cx = pt / (fmaxf(sqrtf(pp), 1e-12f) * fmaxf(sqrtf(tt), 1e-12f));
    float cy = qs / (fmaxf(sqrtf(qq), 1e-12f) * fmaxf(sqrtf(ss), 1e-12f));
    float lsum = valid ? (4.f - 2.f * cx - 2.f * cy) : 0.f;
    lsum += __shfl_xor(lsum, 1); lsum += __shfl_xor(lsum, 2);
    lsum += __shfl_xor(lsum, 4); lsum += __shfl_xor(lsum, 8);
    if (lane == 0) lred[wave] = lsum;
    __syncthreads();
    if (threadIdx.x == 0) {
        // 64 line-padded slots: ~12 blocks/slot instead of 782 on one address
        atomicAdd(&lossb[(blockIdx.x & 63) * 16], lred[0] + lred[1] + lred[2] + lred[3]);
        __threadfence();
        int old = atomicAdd(tick, 1);
        lastflag = (old == (int)gridDim.x - 1) ? 1 : 0;
    }
    __syncthreads();
    if (lastflag && threadIdx.x < 64) {
        float v = atomicAdd(&lossb[threadIdx.x * 16], 0.f);   // device-scope read
#pragma unroll
        for (int mm = 1; mm < 64; mm <<= 1) v += __shfl_xor(v, mm);
        if (threadIdx.x == 0) out[(size_t)N * 128] = v * (1.0f / (float)N);
    }
}

extern "C" void kernel_launch(void* const* d_in, const int* in_sizes, int n_in,
                              void* d_out, int out_size, void* d_ws, size_t ws_size,
                              hipStream_t stream)
{
    const float* x    = (const float*)d_in[0];
    const float* perb = (const float*)d_in[1];
    const int*   erow = (const int*)d_in[2];
    const int*   ecol = (const int*)d_in[3];
    const float* ew   = (const float*)d_in[4];
    const float* Won  = (const float*)d_in[5];
    const float* bon  = (const float*)d_in[6];
    const float* Wtg  = (const float*)d_in[7];
    const float* btg  = (const float*)d_in[8];
    const float* W1   = (const float*)d_in[9];
    const float* b1   = (const float*)d_in[10];
    const float* bng  = (const float*)d_in[11];
    const float* bnb  = (const float*)d_in[12];
    const float* pra  = (const float*)d_in[13];
    const float* W2   = (const float*)d_in[14];
    const float* b2   = (const float*)d_in[15];
    float* out = (float*)d_out;

    const int N = in_sizes[0] / 128;
    const int E = in_sizes[2];

    char* ws = (char*)d_ws;
    u16* XS  = (u16*)ws;
    u16* AG  = (u16*)(ws + (size_t)N * 512);
    u16* h1x = (u16*)(ws + (size_t)N * 1024);
    u16* h1y = (u16*)(ws + (size_t)N * 1024 + (size_t)N * 256);

    char* p = ws + (size_t)N * 1024 + (size_t)N * 512;
    const size_t szcnt = (((size_t)(N + 16) * 4) + 63) & ~(size_t)63;
    int* cnt  = (int*)p;      p += szcnt;
    float* sums = (float*)p;  p += 2048;
    float* lossb = (float*)p; p += 4096;   // 64 slots x 16 floats
    int* ticks = (int*)p;     p += 64;
    size_t zero_bytes = (size_t)(p - (char*)cnt);
    int* off  = (int*)p;      p += szcnt;
    int* bsum = (int*)p;      p += 4096;
    uint2* cpack = (uint2*)p; p += (((size_t)E * 8) + 63) & ~(size_t)63;
    float* c1 = (float*)p;    p += 512;
    float* bnp = (float*)p;   p += 2048;
    float* Wc = (float*)p;    p += 128 * 128 * 4;
    u16* Wfrag = (u16*)p;     p += 4 * 16384 * 2;

    hipMemsetAsync(cnt, 0, zero_bytes, stream);

    const int nb64 = (N + 63) / 64;
    const int nbscan = (N + SCAN_CHUNK - 1) / SCAN_CHUNK;
    const int NS = (N * 32 + 255) / 256;
    const int NC = (E + 255) / 256;

    k_front<<<65 + NS + NC, 256, 0, stream>>>(x, perb, erow, Won, W1, bon, b1,
                                              XS, cnt, Wc, c1, N, E, NS);
    k_mid<<<4 + nbscan, 256, 0, stream>>>(Won, Wtg, Wc, W2, Wfrag, cnt, bsum, N, nbscan);
    k_scan2<<<nbscan, 256, 0, stream>>>(cnt, bsum, off, N, E);
    k_scatter<<<NC, 256, 0, stream>>>(erow, ecol, ew, off, cnt, cpack, E);
    k_agg<<<(N + 3) / 4, 256, 0, stream>>>(XS, off, cpack, AG, N);
    k_hemb<<<nb64, 256, 0, stream>>>(AG, Wfrag, c1, bon, x, perb, h1x, h1y, out, N);
    k_bnstats<<<128, 256, 0, stream>>>((const u32*)h1x, (const u32*)h1y, sums, ticks, bng, bnb, bnp, N);
    k_loss<<<nb64, 256, 0, stream>>>(h1x, h1y, AG, Wfrag, bnp, pra, b2, btg, lossb, ticks + 1, out, N);
}

// Round 8
// 381.829 us; speedup vs baseline: 1.6026x; 1.6026x over previous
//
#include <hip/hip_runtime.h>

typedef unsigned int u32;
typedef unsigned short u16;
typedef unsigned long long u64;
typedef __attribute__((ext_vector_type(8))) short short8;
typedef __attribute__((ext_vector_type(4))) float floatx4;

union F8 { uint4 u4; short8 s8; };

__device__ __forceinline__ float bf2f(u32 lo16) { return __uint_as_float(lo16 << 16); }
__device__ __forceinline__ u16 f2bf(float f) {
    u32 u = __float_as_uint(f);
    return (u16)((u + 0x7FFFu + ((u >> 16) & 1u)) >> 16);
}
__device__ __forceinline__ u32 pack2(float a, float b) {
    return (u32)f2bf(a) | ((u32)f2bf(b) << 16);
}

// ---------------- k_front: blocks [0,64)=Wc, 64=c1, [65,65+NS)=stage, rest=count
__global__ __launch_bounds__(256) void k_front(
    const float* __restrict__ x, const float* __restrict__ perb,
    const int* __restrict__ erow,
    const float* __restrict__ Won, const float* __restrict__ W1,
    const float* __restrict__ b_on, const float* __restrict__ b1,
    u16* __restrict__ XS, int* __restrict__ cnt,
    float* __restrict__ Wc, float* __restrict__ c1,
    int N, int E, int NS)
{
    int b = blockIdx.x, t = threadIdx.x;
    if (b < 64) {
        int tid = b * 256 + t;
        int i = tid >> 7, j = tid & 127;
        float s = 0.f;
        for (int k = 0; k < 128; k++) s = fmaf(Won[i * 128 + k], W1[k * 128 + j], s);
        Wc[tid] = s;
    } else if (b == 64) {
        if (t < 128) {
            float s = b1[t];
            for (int k = 0; k < 128; k++) s = fmaf(b_on[k], W1[k * 128 + t], s);
            c1[t] = s;
        }
    } else if (b < 65 + NS) {
        int tid = (b - 65) * 256 + t;
        if (tid < N * 32) {
            int row = tid >> 5, seg = tid & 31;
            float4 xv = *(const float4*)(x + (size_t)row * 128 + seg * 4);
            float4 pv = *(const float4*)(perb + (size_t)row * 128 + seg * 4);
            u16* r = XS + (size_t)row * 256 + seg * 4;
            *(uint2*)r = make_uint2(pack2(xv.x, xv.y), pack2(xv.z, xv.w));
            *(uint2*)(r + 128) = make_uint2(pack2(xv.x + pv.x, xv.y + pv.y), pack2(xv.z + pv.z, xv.w + pv.w));
        }
    } else {
        int e = (b - 65 - NS) * 256 + t;
        if (e < E) atomicAdd(&cnt[erow[e]], 1);
    }
}

#define SCAN_CHUNK 512
// ---------------- k_mid: blocks [0,4)=wfrag, rest=bsum
__global__ __launch_bounds__(256) void k_mid(
    const float* __restrict__ Won, const float* __restrict__ Wtg,
    const float* __restrict__ Wc, const float* __restrict__ W2,
    u16* __restrict__ Wfrag,
    const int* __restrict__ cnt, int* __restrict__ bsum, int N, int nbscan)
{
    __shared__ int red[256];
    int b = blockIdx.x, t = threadIdx.x;
    if (b < 4) {
        int mat = b;
        const float* W = mat == 0 ? Won : (mat == 1 ? Wtg : (mat == 2 ? Wc : W2));
        uint4* out = (uint4*)(Wfrag + (size_t)mat * 16384);
        for (int s = t; s < 2048; s += 256) {
            int lane = s & 63;
            int n = ((s >> 8) << 4) + (lane & 15);
            int k0 = ((s >> 6) & 3) * 32 + (lane >> 4) * 8;
            u32 p[4];
#pragma unroll
            for (int jj = 0; jj < 4; jj++) {
                float a = W[(size_t)(k0 + 2 * jj) * 128 + n];
                float bb = W[(size_t)(k0 + 2 * jj + 1) * 128 + n];
                p[jj] = pack2(a, bb);
            }
            out[s] = make_uint4(p[0], p[1], p[2], p[3]);
        }
    } else {
        int bb = b - 4;
        if (bb >= nbscan) return;
        int i0 = bb * SCAN_CHUNK + t;
        int s = 0;
        if (i0 < N) s += cnt[i0];
        if (i0 + 256 < N) s += cnt[i0 + 256];
        red[t] = s; __syncthreads();
        for (int d = 128; d > 0; d >>= 1) { if (t < d) red[t] += red[t + d]; __syncthreads(); }
        if (t == 0) bsum[bb] = red[0];
    }
}

__global__ __launch_bounds__(256) void k_scan2(
    const int* __restrict__ cnt, const int* __restrict__ bsum,
    int* __restrict__ off, int N, int E)
{
    int b = blockIdx.x, t = threadIdx.x;
    __shared__ int red[256];
    __shared__ int sc[257];
    __shared__ int sbase;
    int ps = 0;
    for (int i = t; i < b; i += 256) ps += bsum[i];
    red[t] = ps; __syncthreads();
    for (int d = 128; d > 0; d >>= 1) { if (t < d) red[t] += red[t + d]; __syncthreads(); }
    if (t == 0) sbase = red[0];
    __syncthreads();
    int base = b * SCAN_CHUNK;
    int i0 = base + 2 * t, i1 = i0 + 1;
    int v0 = (i0 < N) ? cnt[i0] : 0;
    int v1 = (i1 < N) ? cnt[i1] : 0;
    int tsum = v0 + v1;
    sc[t] = tsum; __syncthreads();
    for (int d = 1; d < 256; d <<= 1) {
        int add = (t >= d) ? sc[t - d] : 0;
        __syncthreads();
        sc[t] += add;
        __syncthreads();
    }
    int excl = sbase + sc[t] - tsum;
    if (i0 < N) off[i0] = excl;
    if (i1 < N) off[i1] = excl + v0;
    if (b == 0 && t == 0) off[N] = E;
}

// ---------------- k_scatter: packed (col,w) single 8B nontemporal store; cnt countdown
__global__ void k_scatter(const int* __restrict__ row, const int* __restrict__ col, const float* __restrict__ w,
                          const int* __restrict__ off, int* __restrict__ cnt,
                          u64* __restrict__ cpack, int E) {
    int e = blockIdx.x * blockDim.x + threadIdx.x;
    if (e < E) {
        int r = row[e];
        int pos = off[r] + atomicSub(&cnt[r], 1) - 1;
        u64 rec = (u64)(u32)col[e] | ((u64)__float_as_uint(w[e]) << 32);
        __builtin_nontemporal_store(rec, &cpack[pos]);
    }
}

// ---------------- k_agg: wave per node; 512B coalesced gather per edge, deep unroll for MLP
__global__ __launch_bounds__(256) void k_agg(
    const u16* __restrict__ XS, const int* __restrict__ off,
    const u64* __restrict__ cpack, u16* __restrict__ AG, int N)
{
    int wave = threadIdx.x >> 6, lane = threadIdx.x & 63;
    int node = blockIdx.x * 4 + wave;
    if (node >= N) return;
    int o0 = off[node], o1 = off[node + 1];
    float a0 = 0.f, a1 = 0.f, a2 = 0.f, a3 = 0.f;
#pragma unroll 8
    for (int e = o0; e < o1; e++) {
        u64 rec = cpack[e];
        int c = (int)(u32)(rec & 0xffffffffu);
        float w = __uint_as_float((u32)(rec >> 32));
        uint2 v = ((const uint2*)(XS + (size_t)c * 256))[lane];
        a0 = fmaf(w, bf2f(v.x & 0xffffu), a0);
        a1 = fmaf(w, bf2f(v.x >> 16), a1);
        a2 = fmaf(w, bf2f(v.y & 0xffffu), a2);
        a3 = fmaf(w, bf2f(v.y >> 16), a3);
    }
    ((uint2*)(AG + (size_t)node * 256))[lane] = make_uint2(pack2(a0, a1), pack2(a2, a3));
}

// ---------------- k_hemb: W fragments staged in LDS (Won + Wc = 64 KB)
__global__ __launch_bounds__(256) void k_hemb(
    const u16* __restrict__ AG, const u16* __restrict__ Wfrag,
    const float* __restrict__ c1, const float* __restrict__ b_on,
    const float* __restrict__ x, const float* __restrict__ perb,
    u16* __restrict__ h1x, u16* __restrict__ h1y, float* __restrict__ out, int N)
{
    __shared__ uint4 sW[4096];
    const int wave = threadIdx.x >> 6, lane = threadIdx.x & 63;
    const int m = lane & 15, q = lane >> 4;
    const int grow = blockIdx.x * 64 + wave * 16 + m;
    const int rc = grow < N ? grow : N - 1;
    const bool valid = grow < N;
    const u16* ar = AG + (size_t)rc * 256;
    const uint4* wfWon = (const uint4*)Wfrag;
    const uint4* wfWc  = (const uint4*)(Wfrag + 2 * 16384);
    short8 fa[4], fb[4];
#pragma unroll
    for (int ks = 0; ks < 4; ks++) {
        int c0 = ks * 32 + q * 8;
        F8 t;
        t.u4 = *(const uint4*)(ar + c0);       fa[ks] = t.s8;
        t.u4 = *(const uint4*)(ar + 128 + c0); fb[ks] = t.s8;
    }
#pragma unroll
    for (int i = threadIdx.x; i < 2048; i += 256) {
        sW[i]        = wfWon[i];
        sW[i + 2048] = wfWc[i];
    }
    __syncthreads();
#pragma unroll 2
    for (int ct = 0; ct < 8; ct++) {
        floatx4 ax = {0.f, 0.f, 0.f, 0.f}, ay = {0.f, 0.f, 0.f, 0.f}, em = {0.f, 0.f, 0.f, 0.f};
#pragma unroll
        for (int ks = 0; ks < 4; ks++) {
            F8 wc, wo;
            wo.u4 = sW[(ct * 4 + ks) * 64 + lane];
            wc.u4 = sW[2048 + (ct * 4 + ks) * 64 + lane];
            ax = __builtin_amdgcn_mfma_f32_16x16x32_bf16(wc.s8, fa[ks], ax, 0, 0, 0);
            ay = __builtin_amdgcn_mfma_f32_16x16x32_bf16(wc.s8, fb[ks], ay, 0, 0, 0);
            em = __builtin_amdgcn_mfma_f32_16x16x32_bf16(wo.s8, fb[ks], em, 0, 0, 0);
        }
        if (valid) {
            int c0 = ct * 16 + q * 4;
            float4 cv = *(const float4*)(c1 + c0);
            float4 bo = *(const float4*)(b_on + c0);
            float4 xv = *(const float4*)(x + (size_t)grow * 128 + c0);
            float4 pv = *(const float4*)(perb + (size_t)grow * 128 + c0);
            *(uint2*)(h1x + (size_t)grow * 128 + c0) =
                make_uint2(pack2(ax[0] + cv.x, ax[1] + cv.y), pack2(ax[2] + cv.z, ax[3] + cv.w));
            *(uint2*)(h1y + (size_t)grow * 128 + c0) =
                make_uint2(pack2(ay[0] + cv.x, ay[1] + cv.y), pack2(ay[2] + cv.z, ay[3] + cv.w));
            float4 o;
            o.x = xv.x + pv.x + em[0] + bo.x;
            o.y = xv.y + pv.y + em[1] + bo.y;
            o.z = xv.z + pv.z + em[2] + bo.z;
            o.w = xv.w + pv.w + em[3] + bo.w;
            *(float4*)(out + (size_t)grow * 128 + c0) = o;
        }
    }
}

// ---------------- k_bnstats (+ fused bnfin via ticket)
__global__ __launch_bounds__(256) void k_bnstats(
    const u32* __restrict__ h1x32, const u32* __restrict__ h1y32,
    float* __restrict__ sums, int* __restrict__ tick,
    const float* __restrict__ g, const float* __restrict__ beta,
    float* __restrict__ bnp, int N)
{
    int c2 = threadIdx.x & 63, gg = threadIdx.x >> 6;
    int per = (N + gridDim.x - 1) / gridDim.x;
    int r0 = blockIdx.x * per, r1 = r0 + per;
    if (r1 > N) r1 = N;
    float s[8] = {0.f, 0.f, 0.f, 0.f, 0.f, 0.f, 0.f, 0.f};
    for (int r = r0 + gg; r < r1; r += 4) {
        u32 vx = h1x32[(size_t)r * 64 + c2];
        float lo = bf2f(vx & 0xffffu), hi = bf2f(vx >> 16);
        s[0] += lo; s[1] = fmaf(lo, lo, s[1]); s[2] += hi; s[3] = fmaf(hi, hi, s[3]);
        u32 vy = h1y32[(size_t)r * 64 + c2];
        lo = bf2f(vy & 0xffffu); hi = bf2f(vy >> 16);
        s[4] += lo; s[5] = fmaf(lo, lo, s[5]); s[6] += hi; s[7] = fmaf(hi, hi, s[7]);
    }
    __shared__ float red[256][8];
    __shared__ int lastflag;
#pragma unroll
    for (int k = 0; k < 8; k++) red[threadIdx.x][k] = s[k];
    __syncthreads();
    if (gg == 0) {
        float v[8];
#pragma unroll
        for (int k = 0; k < 8; k++)
            v[k] = red[c2][k] + red[c2 + 64][k] + red[c2 + 128][k] + red[c2 + 192][k];
        int c0 = 2 * c2, c1i = c0 + 1;
        atomicAdd(&sums[c0], v[0]);        atomicAdd(&sums[128 + c0], v[1]);
        atomicAdd(&sums[c1i], v[2]);       atomicAdd(&sums[128 + c1i], v[3]);
        atomicAdd(&sums[256 + c0], v[4]);  atomicAdd(&sums[384 + c0], v[5]);
        atomicAdd(&sums[256 + c1i], v[6]); atomicAdd(&sums[384 + c1i], v[7]);
    }
    __syncthreads();
    if (threadIdx.x == 0) {
        __threadfence();
        int old = atomicAdd(tick, 1);
        lastflag = (old == (int)gridDim.x - 1) ? 1 : 0;
    }
    __syncthreads();
    if (lastflag && threadIdx.x < 128) {
        int d = threadIdx.x;
        float inv = 1.0f / (float)N;
        float s0 = atomicAdd(&sums[d], 0.f);
        float s1 = atomicAdd(&sums[128 + d], 0.f);
        float s2 = atomicAdd(&sums[256 + d], 0.f);
        float s3 = atomicAdd(&sums[384 + d], 0.f);
        float mux = s0 * inv;
        float varx = s1 * inv - mux * mux;
        float isx = rsqrtf(varx + 1e-5f);
        bnp[d]       = g[d] * isx;
        bnp[128 + d] = beta[d] - mux * g[d] * isx;
        float muy = s2 * inv;
        float vary = s3 * inv - muy * muy;
        float isy = rsqrtf(vary + 1e-5f);
        bnp[256 + d] = g[d] * isy;
        bnp[384 + d] = beta[d] - muy * g[d] * isy;
    }
}

// ---------------- k_loss (+ fused finalize via ticket; 64-slot spread loss accumulator)
__device__ __forceinline__ short8 bn_frag(const u16* hrow, const float* sc, const float* sh,
                                          int c0, float slope) {
    uint4 h = *(const uint4*)(hrow + c0);
    float4 s0 = *(const float4*)(sc + c0), s1 = *(const float4*)(sc + c0 + 4);
    float4 t0 = *(const float4*)(sh + c0), t1 = *(const float4*)(sh + c0 + 4);
    float v[8];
    v[0] = fmaf(bf2f(h.x & 0xffffu), s0.x, t0.x);
    v[1] = fmaf(bf2f(h.x >> 16),     s0.y, t0.y);
    v[2] = fmaf(bf2f(h.y & 0xffffu), s0.z, t0.z);
    v[3] = fmaf(bf2f(h.y >> 16),     s0.w, t0.w);
    v[4] = fmaf(bf2f(h.z & 0xffffu), s1.x, t1.x);
    v[5] = fmaf(bf2f(h.z >> 16),     s1.y, t1.y);
    v[6] = fmaf(bf2f(h.w & 0xffffu), s1.z, t1.z);
    v[7] = fmaf(bf2f(h.w >> 16),     s1.w, t1.w);
#pragma unroll
    for (int j = 0; j < 8; j++) v[j] = v[j] > 0.f ? v[j] : slope * v[j];
    F8 r;
    r.u4 = make_uint4(pack2(v[0], v[1]), pack2(v[2], v[3]), pack2(v[4], v[5]), pack2(v[6], v[7]));
    return r.s8;
}

__global__ __launch_bounds__(256) void k_loss(
    const u16* __restrict__ h1x, const u16* __restrict__ h1y,
    const u16* __restrict__ AG, const u16* __restrict__ Wfrag,
    const float* __restrict__ bnp, const float* __restrict__ prelu_a,
    const float* __restrict__ b2, const float* __restrict__ b_tg,
    float* __restrict__ lossb, int* __restrict__ tick, float* __restrict__ out, int N)
{
    __shared__ uint4 sW[4096];
    __shared__ float lred[4];
    __shared__ int lastflag;
    const int wave = threadIdx.x >> 6, lane = threadIdx.x & 63;
    const int m = lane & 15, q = lane >> 4;
    const int grow = blockIdx.x * 64 + wave * 16 + m;
    const int rc = grow < N ? grow : N - 1;
    const bool valid = grow < N;
    const float slope = prelu_a[0];
    const u16* hx = h1x + (size_t)rc * 128;
    const u16* hy = h1y + (size_t)rc * 128;
    const u16* ar = AG + (size_t)rc * 256;
    const uint4* wfTg = (const uint4*)(Wfrag + 1 * 16384);
    const uint4* wfW2 = (const uint4*)(Wfrag + 3 * 16384);
    short8 px8[4], py8[4], gx[4], gx2[4];
#pragma unroll
    for (int ks = 0; ks < 4; ks++) {
        int c0 = ks * 32 + q * 8;
        px8[ks] = bn_frag(hx, bnp, bnp + 128, c0, slope);
        py8[ks] = bn_frag(hy, bnp + 256, bnp + 384, c0, slope);
        F8 t;
        t.u4 = *(const uint4*)(ar + c0);       gx[ks] = t.s8;
        t.u4 = *(const uint4*)(ar + 128 + c0); gx2[ks] = t.s8;
    }
#pragma unroll
    for (int i = threadIdx.x; i < 2048; i += 256) {
        sW[i]        = wfTg[i];
        sW[i + 2048] = wfW2[i];
    }
    __syncthreads();
    float pp = 0.f, pt = 0.f, tt = 0.f, qq = 0.f, qs = 0.f, ss = 0.f;
#pragma unroll 2
    for (int ct = 0; ct < 8; ct++) {
        floatx4 ax = {0.f, 0.f, 0.f, 0.f}, ay = {0.f, 0.f, 0.f, 0.f};
        floatx4 atx = {0.f, 0.f, 0.f, 0.f}, aty = {0.f, 0.f, 0.f, 0.f};
#pragma unroll
        for (int ks = 0; ks < 4; ks++) {
            F8 w2, wt;
            wt.u4 = sW[(ct * 4 + ks) * 64 + lane];
            w2.u4 = sW[2048 + (ct * 4 + ks) * 64 + lane];
            ax  = __builtin_amdgcn_mfma_f32_16x16x32_bf16(w2.s8, px8[ks], ax, 0, 0, 0);
            ay  = __builtin_amdgcn_mfma_f32_16x16x32_bf16(w2.s8, py8[ks], ay, 0, 0, 0);
            atx = __builtin_amdgcn_mfma_f32_16x16x32_bf16(wt.s8, gx2[ks], atx, 0, 0, 0);
            aty = __builtin_amdgcn_mfma_f32_16x16x32_bf16(wt.s8, gx[ks], aty, 0, 0, 0);
        }
        int c0 = ct * 16 + q * 4;
        float4 bv = *(const float4*)(b2 + c0);
        float4 tb = *(const float4*)(b_tg + c0);
#pragma unroll
        for (int j = 0; j < 4; j++) {
            float bvj = j == 0 ? bv.x : (j == 1 ? bv.y : (j == 2 ? bv.z : bv.w));
            float tbj = j == 0 ? tb.x : (j == 1 ? tb.y : (j == 2 ? tb.z : tb.w));
            float pxv = ax[j] + bvj, txv = atx[j] + tbj;
            float pyv = ay[j] + bvj, tyv = aty[j] + tbj;
            pp = fmaf(pxv, pxv, pp); pt = fmaf(pxv, txv, pt); tt = fmaf(txv, txv, tt);
            qq = fmaf(pyv, pyv, qq); qs = fmaf(pyv, tyv, qs); ss = fmaf(tyv, tyv, ss);
        }
    }
    pp += __shfl_xor(pp, 16); pt += __shfl_xor(pt, 16); tt += __shfl_xor(tt, 16);
    qq += __shfl_xor(qq, 16); qs += __shfl_xor(qs, 16); ss += __shfl_xor(ss, 16);
    pp += __shfl_xor(pp, 32); pt += __shfl_xor(pt, 32); tt += __shfl_xor(tt, 32);
    qq += __shfl_xor(qq, 32); qs += __shfl_xor(qs, 32); ss += __shfl_xor(ss, 32);
    float cx = pt / (fmaxf(sqrtf(pp), 1e-12f) * fmaxf(sqrtf(tt), 1e-12f));
    float cy = qs / (fmaxf(sqrtf(qq), 1e-12f) * fmaxf(sqrtf(ss), 1e-12f));
    float lsum = valid ? (4.f - 2.f * cx - 2.f * cy) : 0.f;
    lsum += __shfl_xor(lsum, 1); lsum += __shfl_xor(lsum, 2);
    lsum += __shfl_xor(lsum, 4); lsum += __shfl_xor(lsum, 8);
    if (lane == 0) lred[wave] = lsum;
    __syncthreads();
    if (threadIdx.x == 0) {
        atomicAdd(&lossb[(blockIdx.x & 63) * 16], lred[0] + lred[1] + lred[2] + lred[3]);
        __threadfence();
        int old = atomicAdd(tick, 1);
        lastflag = (old == (int)gridDim.x - 1) ? 1 : 0;
    }
    __syncthreads();
    if (lastflag && threadIdx.x < 64) {
        float v = atomicAdd(&lossb[threadIdx.x * 16], 0.f);
#pragma unroll
        for (int mm = 1; mm < 64; mm <<= 1) v += __shfl_xor(v, mm);
        if (threadIdx.x == 0) out[(size_t)N * 128] = v * (1.0f / (float)N);
    }
}

extern "C" void kernel_launch(void* const* d_in, const int* in_sizes, int n_in,
                              void* d_out, int out_size, void* d_ws, size_t ws_size,
                              hipStream_t stream)
{
    const float* x    = (const float*)d_in[0];
    const float* perb = (const float*)d_in[1];
    const int*   erow = (const int*)d_in[2];
    const int*   ecol = (const int*)d_in[3];
    const float* ew   = (const float*)d_in[4];
    const float* Won  = (const float*)d_in[5];
    const float* bon  = (const float*)d_in[6];
    const float* Wtg  = (const float*)d_in[7];
    const float* btg  = (const float*)d_in[8];
    const float* W1   = (const float*)d_in[9];
    const float* b1   = (const float*)d_in[10];
    const float* bng  = (const float*)d_in[11];
    const float* bnb  = (const float*)d_in[12];
    const float* pra  = (const float*)d_in[13];
    const float* W2   = (const float*)d_in[14];
    const float* b2   = (const float*)d_in[15];
    float* out = (float*)d_out;

    const int N = in_sizes[0] / 128;
    const int E = in_sizes[2];

    char* ws = (char*)d_ws;
    u16* XS  = (u16*)ws;
    u16* AG  = (u16*)(ws + (size_t)N * 512);
    u16* h1x = (u16*)(ws + (size_t)N * 1024);
    u16* h1y = (u16*)(ws + (size_t)N * 1024 + (size_t)N * 256);

    char* p = ws + (size_t)N * 1024 + (size_t)N * 512;
    const size_t szcnt = (((size_t)(N + 16) * 4) + 63) & ~(size_t)63;
    int* cnt  = (int*)p;      p += szcnt;
    float* sums = (float*)p;  p += 2048;
    float* lossb = (float*)p; p += 4096;
    int* ticks = (int*)p;     p += 64;
    size_t zero_bytes = (size_t)(p - (char*)cnt);
    int* off  = (int*)p;      p += szcnt;
    int* bsum = (int*)p;      p += 4096;
    u64* cpack = (u64*)p;     p += (((size_t)E * 8) + 63) & ~(size_t)63;
    float* c1 = (float*)p;    p += 512;
    float* bnp = (float*)p;   p += 2048;
    float* Wc = (float*)p;    p += 128 * 128 * 4;
    u16* Wfrag = (u16*)p;     p += 4 * 16384 * 2;

    hipMemsetAsync(cnt, 0, zero_bytes, stream);

    const int nb64 = (N + 63) / 64;
    const int nbscan = (N + SCAN_CHUNK - 1) / SCAN_CHUNK;
    const int NS = (N * 32 + 255) / 256;
    const int NC = (E + 255) / 256;

    k_front<<<65 + NS + NC, 256, 0, stream>>>(x, perb, erow, Won, W1, bon, b1,
                                              XS, cnt, Wc, c1, N, E, NS);
    k_mid<<<4 + nbscan, 256, 0, stream>>>(Won, Wtg, Wc, W2, Wfrag, cnt, bsum, N, nbscan);
    k_scan2<<<nbscan, 256, 0, stream>>>(cnt, bsum, off, N, E);
    k_scatter<<<NC, 256, 0, stream>>>(erow, ecol, ew, off, cnt, cpack, E);
    k_agg<<<(N + 3) / 4, 256, 0, stream>>>(XS, off, cpack, AG, N);
    k_hemb<<<nb64, 256, 0, stream>>>(AG, Wfrag, c1, bon, x, perb, h1x, h1y, out, N);
    k_bnstats<<<128, 256, 0, stream>>>((const u32*)h1x, (const u32*)h1y, sums, ticks, bng, bnb, bnp, N);
    k_loss<<<nb64, 256, 0, stream>>>(h1x, h1y, AG, Wfrag, bnp, pra, b2, btg, lossb, ticks + 1, out, N);
}